// Round 1
// baseline (678.146 us; speedup 1.0000x reference)
//
#include <hip/hip_runtime.h>
#include <hip/hip_bf16.h>
#include <stdint.h>

// Problem constants
#define TOK    8192      // B*S
#define DIN    4096
#define DOUT   4096
#define NEXP   8
#define RK     16
#define NRANK  128       // NEXP*RK
#define KE     4224      // DIN + NRANK (extended K)
#define SEQB   2048      // S (tokens per batch entry)
#define LSCALE 2.0f      // ALPHA/RANK
#define KSPLIT 4
#define KSLICE (DIN / KSPLIT)   // 1024

typedef __attribute__((ext_vector_type(8))) short bf8_t;   // 8 bf16 = 4 VGPRs
typedef __attribute__((ext_vector_type(4))) float f4_t;

__device__ __forceinline__ void async_copy16(const void* g, void* l) {
  __builtin_amdgcn_global_load_lds((const __attribute__((address_space(1))) void*)g,
                                   (__attribute__((address_space(3))) void*)l,
                                   16, 0, 0);
}

__device__ __forceinline__ ushort f2bf(float f) {
  __hip_bfloat16 h = __float2bfloat16(f);
  return *reinterpret_cast<ushort*>(&h);
}

// ---------- conversion kernels (fp32 -> bf16, memory-bound) ----------

// x [TOK, DIN] fp32 -> Xe [TOK, KE] bf16 (cols 0..DIN-1)
__global__ void cvt_x_kernel(const float* __restrict__ x, ushort* __restrict__ Xe) {
  int i = blockIdx.x * 256 + threadIdx.x;          // [0, TOK*DIN/8)
  int t = i / (DIN / 8);
  int c = (i - t * (DIN / 8)) * 8;
  const float4* s = reinterpret_cast<const float4*>(x + (size_t)t * DIN + c);
  float4 a = s[0], b = s[1];
  union { ushort u[8]; uint4 v; } o;
  o.u[0]=f2bf(a.x); o.u[1]=f2bf(a.y); o.u[2]=f2bf(a.z); o.u[3]=f2bf(a.w);
  o.u[4]=f2bf(b.x); o.u[5]=f2bf(b.y); o.u[6]=f2bf(b.z); o.u[7]=f2bf(b.w);
  *reinterpret_cast<uint4*>(Xe + (size_t)t * KE + c) = o.v;
}

// W_base [DOUT, DIN] fp32 -> Wc [DOUT, KE] bf16 (cols 0..DIN-1)
__global__ void cvt_w_kernel(const float* __restrict__ w, ushort* __restrict__ Wc) {
  int i = blockIdx.x * 256 + threadIdx.x;          // [0, DOUT*DIN/8)
  int t = i / (DIN / 8);
  int c = (i - t * (DIN / 8)) * 8;
  const float4* s = reinterpret_cast<const float4*>(w + (size_t)t * DIN + c);
  float4 a = s[0], b = s[1];
  union { ushort u[8]; uint4 v; } o;
  o.u[0]=f2bf(a.x); o.u[1]=f2bf(a.y); o.u[2]=f2bf(a.z); o.u[3]=f2bf(a.w);
  o.u[4]=f2bf(b.x); o.u[5]=f2bf(b.y); o.u[6]=f2bf(b.z); o.u[7]=f2bf(b.w);
  *reinterpret_cast<uint4*>(Wc + (size_t)t * KE + c) = o.v;
}

// lora_up [NEXP, DOUT, RK] fp32 -> Wc [DOUT, KE] bf16 cols DIN + n*RK + r
__global__ void cvt_up_kernel(const float* __restrict__ lu, ushort* __restrict__ Wc) {
  int i = blockIdx.x * 256 + threadIdx.x;          // [0, DOUT*NEXP)
  int o = i >> 3;
  int n = i & 7;
  const float4* s = reinterpret_cast<const float4*>(lu + ((size_t)n * DOUT + o) * RK);
  float4 a = s[0], b = s[1], c = s[2], e = s[3];
  union { ushort u[8]; uint4 v; } t0, t1;
  t0.u[0]=f2bf(a.x); t0.u[1]=f2bf(a.y); t0.u[2]=f2bf(a.z); t0.u[3]=f2bf(a.w);
  t0.u[4]=f2bf(b.x); t0.u[5]=f2bf(b.y); t0.u[6]=f2bf(b.z); t0.u[7]=f2bf(b.w);
  t1.u[0]=f2bf(c.x); t1.u[1]=f2bf(c.y); t1.u[2]=f2bf(c.z); t1.u[3]=f2bf(c.w);
  t1.u[4]=f2bf(e.x); t1.u[5]=f2bf(e.y); t1.u[6]=f2bf(e.z); t1.u[7]=f2bf(e.w);
  ushort* d = Wc + (size_t)o * KE + DIN + n * RK;
  *reinterpret_cast<uint4*>(d)     = t0.v;
  *reinterpret_cast<uint4*>(d + 8) = t1.v;
}

// lora_down [NRANK, DIN] fp32 -> Ld [NRANK, DIN] bf16 (flat)
__global__ void cvt_ld_kernel(const float* __restrict__ src, ushort* __restrict__ dst) {
  int i = (blockIdx.x * 256 + threadIdx.x) * 8;    // [0, NRANK*DIN)
  const float4* s = reinterpret_cast<const float4*>(src + i);
  float4 a = s[0], b = s[1];
  union { ushort u[8]; uint4 v; } o;
  o.u[0]=f2bf(a.x); o.u[1]=f2bf(a.y); o.u[2]=f2bf(a.z); o.u[3]=f2bf(a.w);
  o.u[4]=f2bf(b.x); o.u[5]=f2bf(b.y); o.u[6]=f2bf(b.z); o.u[7]=f2bf(b.w);
  *reinterpret_cast<uint4*>(dst + i) = o.v;
}

// ---------- 128x128 bf16 MFMA GEMM (m97 structure) ----------
// C[m,n] = sum_k A[m,k] * B[n,k]   (B^T layout)
// MODE 0: main GEMM, K=KE, fp32 out to C [TOK, DOUT]
// MODE 1: down GEMM split-K slice (blockIdx.z), fp32 partials to D32 slices
template<int KLEN, int LDB, int MODE>
__global__ __launch_bounds__(256)
void gemm128(const ushort* __restrict__ A,
             const ushort* __restrict__ Bm,
             float* __restrict__ C) {
  __shared__ __align__(16) ushort As[128 * 32];
  __shared__ __align__(16) ushort Bs[128 * 32];

  const int tid  = threadIdx.x;
  const int wave = tid >> 6;
  const int lane = tid & 63;
  const int bm = blockIdx.y * 128;
  const int bn = blockIdx.x * 128;
  const int wm = wave & 1, wn = wave >> 1;

  f4_t acc[4][4];
#pragma unroll
  for (int i = 0; i < 4; i++)
#pragma unroll
    for (int j = 0; j < 4; j++) acc[i][j] = (f4_t){0.f, 0.f, 0.f, 0.f};

  // staging geometry: flat bf16 index f = (p*256 + tid)*8 over the 128x32 tile
  const int f0 = tid * 8;
  const int r0 = f0 >> 5, c0 = f0 & 31;
  const int f1 = (256 + tid) * 8;
  const int r1 = f1 >> 5, c1 = f1 & 31;
  // wave-uniform LDS bases (in elements); lane data lands at +lane*16B
  const int l0 = (wave << 6) * 8;
  const int l1 = (256 + (wave << 6)) * 8;

  const ushort* Ar = As + (wm * 64 + (lane & 15)) * 32 + (lane >> 4) * 8;
  const ushort* Br = Bs + (wn * 64 + (lane & 15)) * 32 + (lane >> 4) * 8;

  const int kbase = (MODE == 1) ? blockIdx.z * KSLICE : 0;
  const int kend  = kbase + KLEN;

  for (int k0 = kbase; k0 < kend; k0 += 32) {
    __syncthreads();
    async_copy16(A  + (size_t)(bm + r0) * KE  + k0 + c0, (void*)(As + l0));
    async_copy16(A  + (size_t)(bm + r1) * KE  + k0 + c1, (void*)(As + l1));
    async_copy16(Bm + (size_t)(bn + r0) * LDB + k0 + c0, (void*)(Bs + l0));
    async_copy16(Bm + (size_t)(bn + r1) * LDB + k0 + c1, (void*)(Bs + l1));
    __syncthreads();
    bf8_t av[4], bv[4];
#pragma unroll
    for (int i = 0; i < 4; i++) av[i] = *(const bf8_t*)(Ar + i * 16 * 32);
#pragma unroll
    for (int j = 0; j < 4; j++) bv[j] = *(const bf8_t*)(Br + j * 16 * 32);
#pragma unroll
    for (int i = 0; i < 4; i++)
#pragma unroll
      for (int j = 0; j < 4; j++)
        acc[i][j] = __builtin_amdgcn_mfma_f32_16x16x32_bf16(av[i], bv[j], acc[i][j], 0, 0, 0);
  }

  if (MODE == 0) {
#pragma unroll
    for (int i = 0; i < 4; i++) {
      int row = bm + wm * 64 + i * 16 + (lane >> 4) * 4;
#pragma unroll
      for (int j = 0; j < 4; j++) {
        int col = bn + wn * 64 + j * 16 + (lane & 15);
#pragma unroll
        for (int rr = 0; rr < 4; rr++)
          C[(size_t)(row + rr) * DOUT + col] = acc[i][j][rr];
      }
    }
  } else {
    // write fp32 partial to slice z of D32 [KSPLIT][TOK][NRANK]
    float* Dz = C + (size_t)blockIdx.z * TOK * NRANK;
#pragma unroll
    for (int i = 0; i < 4; i++) {
      int row = bm + wm * 64 + i * 16 + (lane >> 4) * 4;
#pragma unroll
      for (int j = 0; j < 4; j++) {
        int col = wn * 64 + j * 16 + (lane & 15);
#pragma unroll
        for (int rr = 0; rr < 4; rr++)
          Dz[(size_t)(row + rr) * NRANK + col] = acc[i][j][rr];
      }
    }
  }
}

// reduce split-K slices, scale by routing*LSCALE, pack bf16 into Xe extension cols
__global__ void scale_store_kernel(const float* __restrict__ D32,
                                   const float* __restrict__ rw,
                                   ushort* __restrict__ Xe) {
  int i = blockIdx.x * 256 + threadIdx.x;          // [0, TOK*NRANK/4)
  int t = i >> 5;                                  // token
  int g = (i & 31) * 4;                            // col base (4 cols, same expert)
  size_t base = (size_t)t * NRANK + g;
  const size_t ss = (size_t)TOK * NRANK;
  float4 a = *reinterpret_cast<const float4*>(D32 + base);
  float4 b = *reinterpret_cast<const float4*>(D32 + ss + base);
  float4 c = *reinterpret_cast<const float4*>(D32 + 2 * ss + base);
  float4 d = *reinterpret_cast<const float4*>(D32 + 3 * ss + base);
  int n = g >> 4;                                  // expert index
  int bb = t / SEQB;
  float s = rw[bb * NEXP + n] * LSCALE;
  union { ushort u[4]; uint2 v; } o;
  o.u[0] = f2bf((a.x + b.x + c.x + d.x) * s);
  o.u[1] = f2bf((a.y + b.y + c.y + d.y) * s);
  o.u[2] = f2bf((a.z + b.z + c.z + d.z) * s);
  o.u[3] = f2bf((a.w + b.w + c.w + d.w) * s);
  *reinterpret_cast<uint2*>(Xe + (size_t)t * KE + DIN + g) = o.v;
}

extern "C" void kernel_launch(void* const* d_in, const int* in_sizes, int n_in,
                              void* d_out, int out_size, void* d_ws, size_t ws_size,
                              hipStream_t stream) {
  const float* x  = (const float*)d_in[0];
  const float* rw = (const float*)d_in[1];
  const float* wb = (const float*)d_in[2];
  const float* ld = (const float*)d_in[3];
  const float* lu = (const float*)d_in[4];
  float* out = (float*)d_out;

  // workspace layout (bf16 elements unless noted)
  ushort* Xe  = (ushort*)d_ws;                         // TOK*KE      = 34,603,008 el
  ushort* Wc  = Xe + (size_t)TOK * KE;                 // DOUT*KE     = 17,301,504 el
  ushort* Ldb = Wc + (size_t)DOUT * KE;                // NRANK*DIN   =    524,288 el
  float*  D32 = (float*)(Ldb + (size_t)NRANK * DIN);   // KSPLIT*TOK*NRANK fp32 = 4,194,304 el

  cvt_x_kernel <<<TOK * DIN / 8 / 256, 256, 0, stream>>>(x, Xe);
  cvt_w_kernel <<<DOUT * DIN / 8 / 256, 256, 0, stream>>>(wb, Wc);
  cvt_up_kernel<<<DOUT * NEXP / 256, 256, 0, stream>>>(lu, Wc);
  cvt_ld_kernel<<<NRANK * DIN / 8 / 256, 256, 0, stream>>>(ld, Ldb);

  // down-projection: D32[z] = Xe[:, z*1024:(z+1)*1024] @ Ld^T   (split-K, 256 blocks)
  gemm128<KSLICE, DIN, 1><<<dim3(1, TOK / 128, KSPLIT), 256, 0, stream>>>(Xe, Ldb, D32);
  // reduce + routing scale + pack into Xe extension columns
  scale_store_kernel<<<TOK * NRANK / 4 / 256, 256, 0, stream>>>(D32, rw, Xe);
  // main GEMM: out = Xe[TOK,KE] @ Wc[DOUT,KE]^T
  gemm128<KE, KE, 0><<<dim3(DOUT / 128, TOK / 128), 256, 0, stream>>>(Xe, Wc, out);
}

// Round 2
// 673.443 us; speedup vs baseline: 1.0070x; 1.0070x over previous
//
#include <hip/hip_runtime.h>
#include <hip/hip_bf16.h>
#include <stdint.h>

// Problem constants
#define TOK    8192      // B*S
#define DIN    4096
#define DOUT   4096
#define NEXP   8
#define RK     16
#define NRANK  128       // NEXP*RK
#define KE     4224      // DIN + NRANK (extended K)
#define SEQB   2048      // S (tokens per batch entry)
#define LSCALE 2.0f      // ALPHA/RANK
#define KSPLIT 4
#define KSLICE (DIN / KSPLIT)   // 1024

typedef __attribute__((ext_vector_type(8))) short bf8_t;   // 8 bf16 = 4 VGPRs
typedef __attribute__((ext_vector_type(4))) float f4_t;

__device__ __forceinline__ void async_copy16(const void* g, void* l) {
  __builtin_amdgcn_global_load_lds((const __attribute__((address_space(1))) void*)g,
                                   (__attribute__((address_space(3))) void*)l,
                                   16, 0, 0);
}

__device__ __forceinline__ ushort f2bf(float f) {
  __hip_bfloat16 h = __float2bfloat16(f);
  return *reinterpret_cast<ushort*>(&h);
}

// ---------- fused conversion kernel (fp32 -> bf16, memory-bound) ----------
// One dispatch covers all four conversions; work item = 8 elements.
//   region 0: x  [TOK,DIN]  -> Xe cols 0..DIN-1          (R0 items)
//   region 1: Wb [DOUT,DIN] -> Wc cols 0..DIN-1          (R1 items)
//   region 2: lora_up [N,DOUT,RK] -> Wc cols DIN+n*RK+r  (R2 items)
//   region 3: lora_down flat -> Ldb flat                 (R3 items)
#define R0 (TOK * DIN / 8)        // 4,194,304
#define R1 (DOUT * DIN / 8)       // 2,097,152
#define R2 (DOUT * NEXP * 2)      //    65,536
#define R3 (NRANK * DIN / 8)      //    65,536
#define RTOT (R0 + R1 + R2 + R3)  // 6,422,528  (= 25088 * 256)

__global__ __launch_bounds__(256)
void cvt_all_kernel(const float* __restrict__ x, const float* __restrict__ wb,
                    const float* __restrict__ lu, const float* __restrict__ ld,
                    ushort* __restrict__ Xe, ushort* __restrict__ Wc,
                    ushort* __restrict__ Ldb) {
  int i = blockIdx.x * 256 + threadIdx.x;
  const float* src;
  ushort* dst;
  if (i < R0) {
    int t = i >> 9;                    // DIN/8 = 512
    int c = (i & 511) * 8;
    src = x + (size_t)t * DIN + c;
    dst = Xe + (size_t)t * KE + c;
  } else if (i < R0 + R1) {
    int j = i - R0;
    int t = j >> 9;
    int c = (j & 511) * 8;
    src = wb + (size_t)t * DIN + c;
    dst = Wc + (size_t)t * KE + c;
  } else if (i < R0 + R1 + R2) {
    int j = i - (R0 + R1);
    int o = j >> 4;
    int rem = j & 15;
    int n = rem >> 1;
    int half = rem & 1;
    src = lu + ((size_t)n * DOUT + o) * RK + half * 8;
    dst = Wc + (size_t)o * KE + DIN + n * RK + half * 8;
  } else {
    int j = i - (R0 + R1 + R2);
    src = ld + (size_t)j * 8;
    dst = Ldb + (size_t)j * 8;
  }
  const float4* s = reinterpret_cast<const float4*>(src);
  float4 a = s[0], b = s[1];
  union { ushort u[8]; uint4 v; } o;
  o.u[0]=f2bf(a.x); o.u[1]=f2bf(a.y); o.u[2]=f2bf(a.z); o.u[3]=f2bf(a.w);
  o.u[4]=f2bf(b.x); o.u[5]=f2bf(b.y); o.u[6]=f2bf(b.z); o.u[7]=f2bf(b.w);
  *reinterpret_cast<uint4*>(dst) = o.v;
}

// ---------- 128x128 bf16 MFMA GEMM (m97 structure) ----------
// C[m,n] = sum_k A[m,k] * B[n,k]   (B^T layout)
// MODE 0: main GEMM, K=KE, fp32 out to C [TOK, DOUT]; 1D grid + XCD swizzle
// MODE 1: down GEMM split-K slice (blockIdx.z), fp32 partials to D32 slices
template<int KLEN, int LDB, int MODE>
__global__ __launch_bounds__(256)
void gemm128(const ushort* __restrict__ A,
             const ushort* __restrict__ Bm,
             float* __restrict__ C) {
  __shared__ __align__(16) ushort As[128 * 32];
  __shared__ __align__(16) ushort Bs[128 * 32];

  const int tid  = threadIdx.x;
  const int wave = tid >> 6;
  const int lane = tid & 63;

  int bm, bn;
  if (MODE == 0) {
    // XCD-aware swizzle: bid&7 ~ XCD. Each XCD owns a 4-n-tile stripe
    // (B stripe = 4*128*KE*2B = 4.3 MB ~ one XCD's L2) and sweeps all
    // m-tiles; A streams through shared L3.
    int bid = blockIdx.x;            // 0..2047
    int xcd = bid & 7;
    int idx = bid >> 3;              // 0..255
    int nt  = xcd * 4 + (idx & 3);   // 0..31
    int mt  = idx >> 2;              // 0..63
    bm = mt * 128;
    bn = nt * 128;
  } else {
    bm = blockIdx.y * 128;
    bn = blockIdx.x * 128;
  }
  const int wm = wave & 1, wn = wave >> 1;

  f4_t acc[4][4];
#pragma unroll
  for (int i = 0; i < 4; i++)
#pragma unroll
    for (int j = 0; j < 4; j++) acc[i][j] = (f4_t){0.f, 0.f, 0.f, 0.f};

  // staging geometry: flat bf16 index f = (p*256 + tid)*8 over the 128x32 tile
  const int f0 = tid * 8;
  const int r0 = f0 >> 5, c0 = f0 & 31;
  const int f1 = (256 + tid) * 8;
  const int r1 = f1 >> 5, c1 = f1 & 31;
  // wave-uniform LDS bases (in elements); lane data lands at +lane*16B
  const int l0 = (wave << 6) * 8;
  const int l1 = (256 + (wave << 6)) * 8;

  const ushort* Ar = As + (wm * 64 + (lane & 15)) * 32 + (lane >> 4) * 8;
  const ushort* Br = Bs + (wn * 64 + (lane & 15)) * 32 + (lane >> 4) * 8;

  const int kbase = (MODE == 1) ? blockIdx.z * KSLICE : 0;
  const int kend  = kbase + KLEN;

  for (int k0 = kbase; k0 < kend; k0 += 32) {
    __syncthreads();
    async_copy16(A  + (size_t)(bm + r0) * KE  + k0 + c0, (void*)(As + l0));
    async_copy16(A  + (size_t)(bm + r1) * KE  + k0 + c1, (void*)(As + l1));
    async_copy16(Bm + (size_t)(bn + r0) * LDB + k0 + c0, (void*)(Bs + l0));
    async_copy16(Bm + (size_t)(bn + r1) * LDB + k0 + c1, (void*)(Bs + l1));
    __syncthreads();
    bf8_t av[4], bv[4];
#pragma unroll
    for (int i = 0; i < 4; i++) av[i] = *(const bf8_t*)(Ar + i * 16 * 32);
#pragma unroll
    for (int j = 0; j < 4; j++) bv[j] = *(const bf8_t*)(Br + j * 16 * 32);
#pragma unroll
    for (int i = 0; i < 4; i++)
#pragma unroll
      for (int j = 0; j < 4; j++)
        acc[i][j] = __builtin_amdgcn_mfma_f32_16x16x32_bf16(av[i], bv[j], acc[i][j], 0, 0, 0);
  }

  if (MODE == 0) {
#pragma unroll
    for (int i = 0; i < 4; i++) {
      int row = bm + wm * 64 + i * 16 + (lane >> 4) * 4;
#pragma unroll
      for (int j = 0; j < 4; j++) {
        int col = bn + wn * 64 + j * 16 + (lane & 15);
#pragma unroll
        for (int rr = 0; rr < 4; rr++)
          C[(size_t)(row + rr) * DOUT + col] = acc[i][j][rr];
      }
    }
  } else {
    // write fp32 partial to slice z of D32 [KSPLIT][TOK][NRANK]
    float* Dz = C + (size_t)blockIdx.z * TOK * NRANK;
#pragma unroll
    for (int i = 0; i < 4; i++) {
      int row = bm + wm * 64 + i * 16 + (lane >> 4) * 4;
#pragma unroll
      for (int j = 0; j < 4; j++) {
        int col = wn * 64 + j * 16 + (lane & 15);
#pragma unroll
        for (int rr = 0; rr < 4; rr++)
          Dz[(size_t)(row + rr) * NRANK + col] = acc[i][j][rr];
      }
    }
  }
}

// reduce split-K slices, scale by routing*LSCALE, pack bf16 into Xe extension cols
__global__ void scale_store_kernel(const float* __restrict__ D32,
                                   const float* __restrict__ rw,
                                   ushort* __restrict__ Xe) {
  int i = blockIdx.x * 256 + threadIdx.x;          // [0, TOK*NRANK/4)
  int t = i >> 5;                                  // token
  int g = (i & 31) * 4;                            // col base (4 cols, same expert)
  size_t base = (size_t)t * NRANK + g;
  const size_t ss = (size_t)TOK * NRANK;
  float4 a = *reinterpret_cast<const float4*>(D32 + base);
  float4 b = *reinterpret_cast<const float4*>(D32 + ss + base);
  float4 c = *reinterpret_cast<const float4*>(D32 + 2 * ss + base);
  float4 d = *reinterpret_cast<const float4*>(D32 + 3 * ss + base);
  int n = g >> 4;                                  // expert index
  int bb = t / SEQB;
  float s = rw[bb * NEXP + n] * LSCALE;
  union { ushort u[4]; uint2 v; } o;
  o.u[0] = f2bf((a.x + b.x + c.x + d.x) * s);
  o.u[1] = f2bf((a.y + b.y + c.y + d.y) * s);
  o.u[2] = f2bf((a.z + b.z + c.z + d.z) * s);
  o.u[3] = f2bf((a.w + b.w + c.w + d.w) * s);
  *reinterpret_cast<uint2*>(Xe + (size_t)t * KE + DIN + g) = o.v;
}

extern "C" void kernel_launch(void* const* d_in, const int* in_sizes, int n_in,
                              void* d_out, int out_size, void* d_ws, size_t ws_size,
                              hipStream_t stream) {
  const float* x  = (const float*)d_in[0];
  const float* rw = (const float*)d_in[1];
  const float* wb = (const float*)d_in[2];
  const float* ld = (const float*)d_in[3];
  const float* lu = (const float*)d_in[4];
  float* out = (float*)d_out;

  // workspace layout (bf16 elements unless noted)
  ushort* Xe  = (ushort*)d_ws;                         // TOK*KE      = 34,603,008 el
  ushort* Wc  = Xe + (size_t)TOK * KE;                 // DOUT*KE     = 17,301,504 el
  ushort* Ldb = Wc + (size_t)DOUT * KE;                // NRANK*DIN   =    524,288 el
  float*  D32 = (float*)(Ldb + (size_t)NRANK * DIN);   // KSPLIT*TOK*NRANK fp32 = 4,194,304 el

  // one fused conversion dispatch (x, W_base, lora_up, lora_down -> bf16)
  cvt_all_kernel<<<RTOT / 256, 256, 0, stream>>>(x, wb, lu, ld, Xe, Wc, Ldb);

  // down-projection: D32[z] = Xe[:, z*1024:(z+1)*1024] @ Ld^T   (split-K, 256 blocks)
  gemm128<KSLICE, DIN, 1><<<dim3(1, TOK / 128, KSPLIT), 256, 0, stream>>>(Xe, Ldb, D32);
  // reduce + routing scale + pack into Xe extension columns
  scale_store_kernel<<<TOK * NRANK / 4 / 256, 256, 0, stream>>>(D32, rw, Xe);
  // main GEMM: out = Xe[TOK,KE] @ Wc[DOUT,KE]^T  (1D grid, XCD swizzle)
  gemm128<KE, KE, 0><<<dim3((TOK / 128) * (DOUT / 128)), 256, 0, stream>>>(Xe, Wc, out);
}